// Round 3
// baseline (1652.120 us; speedup 1.0000x reference)
//
#include <hip/hip_runtime.h>
#include <math.h>

#define D_ 128
#define K_ 1024
#define N_ 65536
#define DECAY_ 0.99f
#define OMD_ 0.01f
#define EPS_ 1e-5f
#define VQC_ 0.25f
#define SSPLIT 4
#define MARGIN_ 0.01f

typedef __attribute__((ext_vector_type(8))) short short8;
typedef __attribute__((ext_vector_type(4))) float f32x4;

// ---- workspace offsets (in 4-byte elements) ----
#define WOFF_CODE  0          // int[65536]
#define WOFF_E2    65536      // float[1024]
#define WOFF_CNT   66560      // int[1024]
#define WOFF_SSQ   67584      // float[1]
#define WOFF_RCNT  67585      // int[1]    (CNT..RCNT zeroed in one memset)
#define WOFF_BASE  67648      // int[1025]
#define WOFF_CURS  68736      // int[1024]
#define WOFF_ORDER 69760      // int[65536]
#define WOFF_CS    135296     // float[1024]
#define WOFF_ET    136320     // float[131072] (K x D), 16B aligned
#define WOFF_PART  267392     // float[SSPLIT * 131072]
#define WOFF_RLIST 791680     // int[65536]
#define WOFF_EFH   857216     // ushort[131072] frag-ordered bf16 hi of -2E
#define WOFF_EFL   922752     // ushort[131072] frag-ordered bf16 lo
// total ~988K elements (~3.95 MB)

// ---- output offsets (in floats), reference return order ----
#define OOFF_Q     0          // [16,4096,128]
#define OOFF_DIFF  8388608    // scalar
#define OOFF_CODE  8388609    // [16,4096]
#define OOFF_NEMB  8454145    // [128,1024]
#define OOFF_NCS   8585217    // [1024]
#define OOFF_NMEAN 8586241    // [128,1024]

// RNE float->bf16, also returns residual (f - bf16(f))
__device__ __forceinline__ unsigned short bf16h(float f, float* rez) {
    unsigned u = __float_as_uint(f);
    unsigned r = (u + 0x7fffu + ((u >> 16) & 1u)) >> 16;
    *rez = f - __uint_as_float(r << 16);
    return (unsigned short)r;
}

// -------------------------------------------------------------------
// E [D][K] -> Et [K][D]
__global__ void k_transpose(const float* __restrict__ E, float* __restrict__ Et) {
    __shared__ float tile[32][33];
    int k0 = blockIdx.x * 32;
    int d0 = blockIdx.y * 32;
    int tx = threadIdx.x;            // 0..31
    for (int ty = threadIdx.y; ty < 32; ty += 8)
        tile[ty][tx] = E[(d0 + ty) * K_ + (k0 + tx)];
    __syncthreads();
    for (int ty = threadIdx.y; ty < 32; ty += 8)
        Et[(k0 + ty) * D_ + (d0 + tx)] = tile[tx][ty];
}

// e2[k] = sum_d E[d][k]^2  (coalesced over k)
__global__ void k_e2(const float* __restrict__ E, float* __restrict__ e2) {
    int k = blockIdx.x * blockDim.x + threadIdx.x;
    float s = 0.f;
    #pragma unroll 8
    for (int d = 0; d < D_; ++d) { float v = E[d * K_ + k]; s = fmaf(v, v, s); }
    e2[k] = s;
}

// -------------------------------------------------------------------
// Build fragment-ordered bf16 hi/lo planes of g = -2*E.
// Layout: index T = ((g16*4 + s)*64 + L); lane L holds code g16*16+(L&15),
// dims s*32 + (L>>4)*8 .. +8  => B-operand frag for mfma 16x16x32.
__global__ void k_prep_ef(const float* __restrict__ Et, unsigned short* __restrict__ Efh,
                          unsigned short* __restrict__ Efl) {
    int T = blockIdx.x * 256 + threadIdx.x;   // 0..16383
    int L = T & 63, s = (T >> 6) & 3, g = T >> 8;
    int code = g * 16 + (L & 15);
    int d0 = s * 32 + ((L >> 4) << 3);
    const float* src = Et + code * D_ + d0;
    unsigned short h[8], l[8];
    #pragma unroll
    for (int j = 0; j < 8; ++j) {
        float v = -2.f * src[j];
        float r;
        h[j] = bf16h(v, &r);
        float r2;
        l[j] = bf16h(r, &r2);
    }
    #pragma unroll
    for (int j = 0; j < 8; ++j) { Efh[T * 8 + j] = h[j]; Efl[T * 8 + j] = l[j]; }
}

// -------------------------------------------------------------------
// MFMA argmin: dist = e2[k] + x.(-2e) via bf16 hi/lo split (3 MFMA terms).
// Block: 256 thr / 4 waves; 128 tokens per block; codes swept in 64-chunks.
// Per wave: 2 m-tiles x 4 n-tiles, acc init = e2 (so final acc == dist).
__launch_bounds__(256, 2)
__global__ void k_argmin_mfma(const float* __restrict__ x, const unsigned short* __restrict__ Efh,
                              const unsigned short* __restrict__ Efl, const float* __restrict__ e2,
                              int* __restrict__ code_i, float* __restrict__ code_f,
                              int* __restrict__ cnt, int* __restrict__ rcnt,
                              int* __restrict__ rlist) {
    __shared__ unsigned short Bs[16384];  // 32 KB: hi plane [0,8192), lo plane [8192,16384)
    __shared__ float e2s[K_];
    int tid = threadIdx.x;
    int w = tid >> 6, L = tid & 63, quad = L >> 4, col = L & 15;
    int n0 = blockIdx.x * 128;

    for (int i = tid; i < K_; i += 256) e2s[i] = e2[i];

    // ---- A fragments: 32 tokens/wave, converted to bf16 hi/lo in registers ----
    short8 ah[2][4], al[2][4];
    #pragma unroll
    for (int mt = 0; mt < 2; ++mt) {
        int tok = n0 + w * 32 + mt * 16 + col;
        #pragma unroll
        for (int s = 0; s < 4; ++s) {
            const float* p = x + (size_t)tok * D_ + s * 32 + quad * 8;
            float4 u0 = *(const float4*)(p);
            float4 u1 = *(const float4*)(p + 4);
            float vv[8] = {u0.x, u0.y, u0.z, u0.w, u1.x, u1.y, u1.z, u1.w};
            #pragma unroll
            for (int j = 0; j < 8; ++j) {
                float r;
                ah[mt][s][j] = (short)bf16h(vv[j], &r);
                float r2;
                al[mt][s][j] = (short)bf16h(r, &r2);
            }
        }
    }

    float b1[2][4];   // running min dist per (m-tile, reg)
    int   bi[2][4];
    float rk[2][4];   // min |d - best_pre| seen (near-tie detector)
    #pragma unroll
    for (int mt = 0; mt < 2; ++mt)
        #pragma unroll
        for (int r = 0; r < 4; ++r) { b1[mt][r] = INFINITY; bi[mt][r] = 0; rk[mt][r] = INFINITY; }

    for (int q = 0; q < 16; ++q) {
        __syncthreads();
        // ---- stage 64-code chunk: flat 16 KB copy per plane ----
        const float4* gh = (const float4*)(Efh + q * 8192);
        const float4* gl = (const float4*)(Efl + q * 8192);
        #pragma unroll
        for (int i = 0; i < 4; ++i) {
            float4 v = gh[i * 256 + tid];
            *(float4*)(Bs + (i * 256 + tid) * 8) = v;
        }
        #pragma unroll
        for (int i = 0; i < 4; ++i) {
            float4 v = gl[i * 256 + tid];
            *(float4*)(Bs + 8192 + (i * 256 + tid) * 8) = v;
        }
        __syncthreads();

        // ---- acc init = e2 of this lane's column ----
        f32x4 acc[2][4];
        #pragma unroll
        for (int n = 0; n < 4; ++n) {
            float ev = e2s[q * 64 + n * 16 + col];
            #pragma unroll
            for (int mt = 0; mt < 2; ++mt) acc[mt][n] = (f32x4){ev, ev, ev, ev};
        }

        // ---- 96 MFMA: 4 k-steps x 4 n-tiles x 2 m-tiles x 3 split terms ----
        #pragma unroll
        for (int s = 0; s < 4; ++s) {
            short8 bh[4], bl[4];
            #pragma unroll
            for (int n = 0; n < 4; ++n) {
                int off = ((n * 4 + s) * 64 + L) * 8;
                bh[n] = *(const short8*)(Bs + off);
                bl[n] = *(const short8*)(Bs + 8192 + off);
            }
            #pragma unroll
            for (int n = 0; n < 4; ++n) {
                #pragma unroll
                for (int mt = 0; mt < 2; ++mt) {
                    acc[mt][n] = __builtin_amdgcn_mfma_f32_16x16x32_bf16(ah[mt][s], bh[n], acc[mt][n], 0, 0, 0);
                    acc[mt][n] = __builtin_amdgcn_mfma_f32_16x16x32_bf16(al[mt][s], bh[n], acc[mt][n], 0, 0, 0);
                    acc[mt][n] = __builtin_amdgcn_mfma_f32_16x16x32_bf16(ah[mt][s], bl[n], acc[mt][n], 0, 0, 0);
                }
            }
        }

        // ---- fold into running argmin (ascending code idx => first-min) ----
        #pragma unroll
        for (int n = 0; n < 4; ++n) {
            int ci = q * 64 + n * 16 + col;
            #pragma unroll
            for (int mt = 0; mt < 2; ++mt) {
                #pragma unroll
                for (int r = 0; r < 4; ++r) {
                    float d = acc[mt][n][r];
                    float t = d - b1[mt][r];
                    rk[mt][r] = fminf(rk[mt][r], fabsf(t));
                    if (d < b1[mt][r]) { b1[mt][r] = d; bi[mt][r] = ci; }
                }
            }
        }
    }

    // ---- cross-lane merge over the 16 lanes of each quad-group ----
    #pragma unroll
    for (int mt = 0; mt < 2; ++mt) {
        #pragma unroll
        for (int r = 0; r < 4; ++r) {
            float bd = b1[mt][r];
            int   ii = bi[mt][r];
            float rr = rk[mt][r];
            #pragma unroll
            for (int m = 1; m < 16; m <<= 1) {
                float ob = __shfl_xor(bd, m);
                int   oi = __shfl_xor(ii, m);
                float orr = __shfl_xor(rr, m);
                rr = fminf(fminf(rr, orr), fabsf(bd - ob));
                if (ob < bd || (ob == bd && oi < ii)) { bd = ob; ii = oi; }
            }
            if (col == 0) {
                int tok = n0 + w * 32 + mt * 16 + quad * 4 + r;
                code_i[tok] = ii;
                code_f[tok] = (float)ii;
                atomicAdd(cnt + ii, 1);
                if (rr < MARGIN_) {
                    int p = atomicAdd(rcnt, 1);
                    rlist[p] = tok;
                }
            }
        }
    }
}

// -------------------------------------------------------------------
// exact fp32 re-argmin for near-tie tokens; patch code + histogram
__launch_bounds__(256)
__global__ void k_fix(const float* __restrict__ x, const float* __restrict__ Et,
                      const float* __restrict__ e2, const int* __restrict__ rcnt,
                      const int* __restrict__ rlist, int* __restrict__ code_i,
                      float* __restrict__ code_f, int* __restrict__ cnt) {
    __shared__ float4 xs[32];
    __shared__ float rd[256];
    __shared__ int   ri[256];
    int tid = threadIdx.x;
    int nr = *rcnt;
    for (int it = blockIdx.x; it < nr; it += gridDim.x) {
        __syncthreads();
        int tok = rlist[it];
        if (tid < 32) xs[tid] = ((const float4*)(x + (size_t)tok * D_))[tid];
        __syncthreads();
        float bd = INFINITY; int bb = 0;
        for (int c = tid; c < K_; c += 256) {
            const float4* er = (const float4*)(Et + c * D_);
            float dot = 0.f;
            #pragma unroll 8
            for (int j = 0; j < 32; ++j) {
                float4 e = er[j], xx = xs[j];
                dot = fmaf(xx.x, e.x, dot);
                dot = fmaf(xx.y, e.y, dot);
                dot = fmaf(xx.z, e.z, dot);
                dot = fmaf(xx.w, e.w, dot);
            }
            float dist = e2[c] - 2.f * dot;
            if (dist < bd) { bd = dist; bb = c; }   // c ascending per thread
        }
        rd[tid] = bd; ri[tid] = bb;
        __syncthreads();
        for (int off = 128; off > 0; off >>= 1) {
            if (tid < off) {
                float d2 = rd[tid + off]; int i2 = ri[tid + off];
                if (d2 < rd[tid] || (d2 == rd[tid] && i2 < ri[tid])) { rd[tid] = d2; ri[tid] = i2; }
            }
            __syncthreads();
        }
        if (tid == 0) {
            int nb = ri[0], ob = code_i[tok];
            if (nb != ob) {
                code_i[tok] = nb;
                code_f[tok] = (float)nb;
                atomicAdd(cnt + ob, -1);
                atomicAdd(cnt + nb, 1);
            }
        }
    }
}

// -------------------------------------------------------------------
// exclusive scan of code histogram -> base, cursor
__launch_bounds__(1024)
__global__ void k_scan(const int* __restrict__ cnt, int* __restrict__ base,
                       int* __restrict__ cursor) {
    int k = threadIdx.x;
    __shared__ int sc[1024];
    int c = cnt[k];
    sc[k] = c;
    __syncthreads();
    for (int off = 1; off < 1024; off <<= 1) {
        int v = (k >= off) ? sc[k - off] : 0;
        __syncthreads();
        sc[k] += v;
        __syncthreads();
    }
    int inc = sc[k];
    base[k + 1] = inc;
    cursor[k]   = inc - c;   // exclusive
    if (k == 0) base[0] = 0;
}

// -------------------------------------------------------------------
// dequant gather + straight-through + diff partial + token-index scatter
__launch_bounds__(256)
__global__ void k_gather(const float* __restrict__ x, const float* __restrict__ Et,
                         const int* __restrict__ code_i, float* __restrict__ outq,
                         int* __restrict__ cursor, int* __restrict__ order,
                         float* __restrict__ ssq) {
    int e4 = blockIdx.x * 256 + threadIdx.x;   // float4 index over N*D/4
    int n = e4 >> 5, q = e4 & 31;
    int c = code_i[n];
    float4 xi = ((const float4*)x)[e4];
    float4 qv = ((const float4*)Et)[c * 32 + q];
    float4 qs;  // straight-through: x + (q - x), matching reference rounding
    qs.x = xi.x + (qv.x - xi.x);
    qs.y = xi.y + (qv.y - xi.y);
    qs.z = xi.z + (qv.z - xi.z);
    qs.w = xi.w + (qv.w - xi.w);
    ((float4*)outq)[e4] = qs;
    float dx = qs.x - xi.x, dy = qs.y - xi.y, dz = qs.z - xi.z, dw = qs.w - xi.w;
    float loc = dx * dx + dy * dy + dz * dz + dw * dw;

    if (q == 0) {
        int pos = atomicAdd(cursor + c, 1);
        order[pos] = n;
    }

    // block reduction of squared-diff
    #pragma unroll
    for (int off = 32; off > 0; off >>= 1) loc += __shfl_down(loc, off);
    __shared__ float wsum[4];
    if ((threadIdx.x & 63) == 0) wsum[threadIdx.x >> 6] = loc;
    __syncthreads();
    if (threadIdx.x == 0) atomicAdd(ssq, wsum[0] + wsum[1] + wsum[2] + wsum[3]);
}

// -------------------------------------------------------------------
// segment sum via sorted token lists: block (c, s) sums 1/SSPLIT of code c
__launch_bounds__(128)
__global__ void k_segsum(const float* __restrict__ x, const int* __restrict__ order,
                         const int* __restrict__ base, float* __restrict__ part) {
    int c = blockIdx.x, s = blockIdx.y, d = threadIdx.x;
    int b0 = base[c], b1 = base[c + 1];
    int cnt = b1 - b0;
    int i0 = b0 + (cnt * s) / SSPLIT;
    int i1 = b0 + (cnt * (s + 1)) / SSPLIT;
    float a0 = 0.f, a1 = 0.f, a2 = 0.f, a3 = 0.f;
    int i = i0;
    for (; i + 4 <= i1; i += 4) {
        int n0 = order[i], n1 = order[i + 1], n2 = order[i + 2], n3 = order[i + 3];
        a0 += x[(size_t)n0 * D_ + d];
        a1 += x[(size_t)n1 * D_ + d];
        a2 += x[(size_t)n2 * D_ + d];
        a3 += x[(size_t)n3 * D_ + d];
    }
    for (; i < i1; ++i) a0 += x[(size_t)order[i] * D_ + d];
    part[((size_t)s * K_ + c) * D_ + d] = (a0 + a1) + (a2 + a3);
}

// -------------------------------------------------------------------
// EMA cluster size, n-reduction, Laplace smoothing, diff finalize
__launch_bounds__(1024)
__global__ void k_stats(const float* __restrict__ cluster_size, const int* __restrict__ cnt,
                        const float* __restrict__ ssq, float* __restrict__ out_ncs,
                        float* __restrict__ out_diff, float* __restrict__ cs) {
    int k = threadIdx.x;
    float ncs = cluster_size[k] * DECAY_ + OMD_ * (float)cnt[k];
    out_ncs[k] = ncs;
    __shared__ float red[1024];
    red[k] = ncs;
    __syncthreads();
    for (int off = 512; off > 0; off >>= 1) {
        if (k < off) red[k] += red[k + off];
        __syncthreads();
    }
    float n = red[0];
    cs[k] = (ncs + EPS_) / (n + (float)K_ * EPS_) * n;
    if (k == 0) *out_diff = VQC_ * (*ssq) / (float)(N_ * D_);
}

// -------------------------------------------------------------------
// reduce partials; new_embedding_mean = EMA; new_embedding = mean / cs
__global__ void k_embed(const float* __restrict__ emb_mean_in, const float* __restrict__ part,
                        const float* __restrict__ cs, float* __restrict__ out_nmean,
                        float* __restrict__ out_nemb) {
    int i = blockIdx.x * 256 + threadIdx.x;   // over D*K, layout [D][K]
    int k = i & (K_ - 1);
    int d = i >> 10;
    float es = 0.f;
    #pragma unroll
    for (int s = 0; s < SSPLIT; ++s) es += part[((size_t)s * K_ + k) * D_ + d];
    float nm = emb_mean_in[i] * DECAY_ + OMD_ * es;
    out_nmean[i] = nm;
    out_nemb[i]  = nm / cs[k];
}

// -------------------------------------------------------------------
extern "C" void kernel_launch(void* const* d_in, const int* in_sizes, int n_in,
                              void* d_out, int out_size, void* d_ws, size_t ws_size,
                              hipStream_t stream) {
    const float* x   = (const float*)d_in[0];   // [16,4096,128]
    const float* E   = (const float*)d_in[1];   // [128,1024]
    const float* csz = (const float*)d_in[2];   // [1024]
    const float* em  = (const float*)d_in[3];   // [128,1024]
    float* out = (float*)d_out;
    float* W   = (float*)d_ws;

    int*   code_i = (int*)(W + WOFF_CODE);
    float* e2     = W + WOFF_E2;
    int*   cnt    = (int*)(W + WOFF_CNT);
    float* ssq    = W + WOFF_SSQ;
    int*   rcnt   = (int*)(W + WOFF_RCNT);
    int*   base   = (int*)(W + WOFF_BASE);
    int*   cursor = (int*)(W + WOFF_CURS);
    int*   order  = (int*)(W + WOFF_ORDER);
    float* cs     = W + WOFF_CS;
    float* Et     = W + WOFF_ET;
    float* part   = W + WOFF_PART;
    int*   rlist  = (int*)(W + WOFF_RLIST);
    unsigned short* Efh = (unsigned short*)(W + WOFF_EFH);
    unsigned short* Efl = (unsigned short*)(W + WOFF_EFL);

    // zero cnt[1024] + ssq + rcnt (ws is poisoned 0xAA)
    hipMemsetAsync(cnt, 0, 1026 * sizeof(int), stream);

    k_transpose<<<dim3(32, 4), dim3(32, 8), 0, stream>>>(E, Et);
    k_e2<<<K_ / 256, 256, 0, stream>>>(E, e2);
    k_prep_ef<<<64, 256, 0, stream>>>(Et, Efh, Efl);
    k_argmin_mfma<<<N_ / 128, 256, 0, stream>>>(x, Efh, Efl, e2, code_i,
                                                out + OOFF_CODE, cnt, rcnt, rlist);
    k_fix<<<64, 256, 0, stream>>>(x, Et, e2, rcnt, rlist, code_i, out + OOFF_CODE, cnt);
    k_scan<<<1, 1024, 0, stream>>>(cnt, base, cursor);
    k_gather<<<(N_ * (D_ / 4)) / 256, 256, 0, stream>>>(x, Et, code_i, out + OOFF_Q,
                                                        cursor, order, ssq);
    k_segsum<<<dim3(K_, SSPLIT), 128, 0, stream>>>(x, order, base, part);
    k_stats<<<1, 1024, 0, stream>>>(csz, cnt, ssq, out + OOFF_NCS, out + OOFF_DIFF, cs);
    k_embed<<<(D_ * K_) / 256, 256, 0, stream>>>(em, part, cs, out + OOFF_NMEAN, out + OOFF_NEMB);
}

// Round 4
// 353.439 us; speedup vs baseline: 4.6744x; 4.6744x over previous
//
#include <hip/hip_runtime.h>
#include <math.h>

#define D_ 128
#define K_ 1024
#define N_ 65536
#define DECAY_ 0.99f
#define OMD_ 0.01f
#define EPS_ 1e-5f
#define VQC_ 0.25f
#define SSPLIT 4
#define MARGIN_ 4e-3f

typedef __attribute__((ext_vector_type(8))) short short8;
typedef __attribute__((ext_vector_type(4))) float f32x4;

// ---- workspace offsets (in 4-byte elements) ----
#define WOFF_CODE  0          // int[65536]
#define WOFF_E2    65536      // float[1024]
#define WOFF_CNT   66560      // int[1024]
#define WOFF_SSQ   67584      // float[1]
#define WOFF_RCNT  67585      // int[1]    (CNT..RCNT zeroed in one memset)
#define WOFF_BASE  67648      // int[1025]
#define WOFF_CURS  68736      // int[1024]
#define WOFF_ORDER 69760      // int[65536]
#define WOFF_CS    135296     // float[1024]
#define WOFF_ET    136320     // float[131072] (K x D), 16B aligned
#define WOFF_PART  267392     // float[SSPLIT * 131072]
#define WOFF_RLIST 791680     // int[65536]
#define WOFF_EFH   857216     // ushort[131072] frag-ordered bf16 hi of -2E
#define WOFF_EFL   922752     // ushort[131072] frag-ordered bf16 lo
// total ~988K elements (~3.95 MB)

// ---- output offsets (in floats), reference return order ----
#define OOFF_Q     0          // [16,4096,128]
#define OOFF_DIFF  8388608    // scalar
#define OOFF_CODE  8388609    // [16,4096]
#define OOFF_NEMB  8454145    // [128,1024]
#define OOFF_NCS   8585217    // [1024]
#define OOFF_NMEAN 8586241    // [128,1024]

// RNE float->bf16, also returns residual (f - bf16(f))
__device__ __forceinline__ unsigned short bf16h(float f, float* rez) {
    unsigned u = __float_as_uint(f);
    unsigned r = (u + 0x7fffu + ((u >> 16) & 1u)) >> 16;
    *rez = f - __uint_as_float(r << 16);
    return (unsigned short)r;
}

// -------------------------------------------------------------------
// E [D][K] -> Et [K][D]
__global__ void k_transpose(const float* __restrict__ E, float* __restrict__ Et) {
    __shared__ float tile[32][33];
    int k0 = blockIdx.x * 32;
    int d0 = blockIdx.y * 32;
    int tx = threadIdx.x;            // 0..31
    for (int ty = threadIdx.y; ty < 32; ty += 8)
        tile[ty][tx] = E[(d0 + ty) * K_ + (k0 + tx)];
    __syncthreads();
    for (int ty = threadIdx.y; ty < 32; ty += 8)
        Et[(k0 + ty) * D_ + (d0 + tx)] = tile[tx][ty];
}

// e2[k] = sum_d E[d][k]^2  (coalesced over k)
__global__ void k_e2(const float* __restrict__ E, float* __restrict__ e2) {
    int k = blockIdx.x * blockDim.x + threadIdx.x;
    float s = 0.f;
    #pragma unroll 8
    for (int d = 0; d < D_; ++d) { float v = E[d * K_ + k]; s = fmaf(v, v, s); }
    e2[k] = s;
}

// -------------------------------------------------------------------
// Build fragment-ordered bf16 hi/lo planes of g = -2*E.
// Layout: index T = ((g16*4 + s)*64 + L); lane L holds code g16*16+(L&15),
// dims s*32 + (L>>4)*8 .. +8  => B-operand frag for mfma 16x16x32.
__global__ void k_prep_ef(const float* __restrict__ Et, unsigned short* __restrict__ Efh,
                          unsigned short* __restrict__ Efl) {
    int T = blockIdx.x * 256 + threadIdx.x;   // 0..16383
    int L = T & 63, s = (T >> 6) & 3, g = T >> 8;
    int code = g * 16 + (L & 15);
    int d0 = s * 32 + ((L >> 4) << 3);
    const float* src = Et + code * D_ + d0;
    unsigned short h[8], l[8];
    #pragma unroll
    for (int j = 0; j < 8; ++j) {
        float v = -2.f * src[j];
        float r;
        h[j] = bf16h(v, &r);
        float r2;
        l[j] = bf16h(r, &r2);
    }
    #pragma unroll
    for (int j = 0; j < 8; ++j) { Efh[T * 8 + j] = h[j]; Efl[T * 8 + j] = l[j]; }
}

// -------------------------------------------------------------------
// MFMA argmin: dist = e2[k] + x.(-2e) via bf16 hi/lo split (3 MFMA terms).
// Block: 256 thr / 4 waves; 128 tokens per block; codes swept in 64-chunks.
// True top-2 (b1,b2) tracked per token => exact near-tie flagging.
__launch_bounds__(256, 2)
__global__ void k_argmin_mfma(const float* __restrict__ x, const unsigned short* __restrict__ Efh,
                              const unsigned short* __restrict__ Efl, const float* __restrict__ e2,
                              int* __restrict__ code_i, float* __restrict__ code_f,
                              int* __restrict__ cnt, int* __restrict__ rcnt,
                              int* __restrict__ rlist) {
    __shared__ unsigned short Bs[16384];  // 32 KB: hi plane [0,8192), lo plane [8192,16384)
    __shared__ float e2s[K_];
    int tid = threadIdx.x;
    int w = tid >> 6, L = tid & 63, quad = L >> 4, col = L & 15;
    int n0 = blockIdx.x * 128;

    for (int i = tid; i < K_; i += 256) e2s[i] = e2[i];

    // ---- A fragments: 32 tokens/wave, converted to bf16 hi/lo in registers ----
    short8 ah[2][4], al[2][4];
    #pragma unroll
    for (int mt = 0; mt < 2; ++mt) {
        int tok = n0 + w * 32 + mt * 16 + col;
        #pragma unroll
        for (int s = 0; s < 4; ++s) {
            const float* p = x + (size_t)tok * D_ + s * 32 + quad * 8;
            float4 u0 = *(const float4*)(p);
            float4 u1 = *(const float4*)(p + 4);
            float vv[8] = {u0.x, u0.y, u0.z, u0.w, u1.x, u1.y, u1.z, u1.w};
            #pragma unroll
            for (int j = 0; j < 8; ++j) {
                float r;
                ah[mt][s][j] = (short)bf16h(vv[j], &r);
                float r2;
                al[mt][s][j] = (short)bf16h(r, &r2);
            }
        }
    }

    float b1[2][4];   // running min dist per (m-tile, reg)
    float b2[2][4];   // running second-best
    int   bi[2][4];
    #pragma unroll
    for (int mt = 0; mt < 2; ++mt)
        #pragma unroll
        for (int r = 0; r < 4; ++r) { b1[mt][r] = INFINITY; b2[mt][r] = INFINITY; bi[mt][r] = 0; }

    for (int q = 0; q < 16; ++q) {
        __syncthreads();
        // ---- stage 64-code chunk: flat 16 KB copy per plane ----
        const float4* gh = (const float4*)(Efh + q * 8192);
        const float4* gl = (const float4*)(Efl + q * 8192);
        #pragma unroll
        for (int i = 0; i < 4; ++i) {
            float4 v = gh[i * 256 + tid];
            *(float4*)(Bs + (i * 256 + tid) * 8) = v;
        }
        #pragma unroll
        for (int i = 0; i < 4; ++i) {
            float4 v = gl[i * 256 + tid];
            *(float4*)(Bs + 8192 + (i * 256 + tid) * 8) = v;
        }
        __syncthreads();

        // ---- acc init = e2 of this lane's column ----
        f32x4 acc[2][4];
        #pragma unroll
        for (int n = 0; n < 4; ++n) {
            float ev = e2s[q * 64 + n * 16 + col];
            #pragma unroll
            for (int mt = 0; mt < 2; ++mt) acc[mt][n] = (f32x4){ev, ev, ev, ev};
        }

        // ---- 96 MFMA: 4 k-steps x 4 n-tiles x 2 m-tiles x 3 split terms ----
        #pragma unroll
        for (int s = 0; s < 4; ++s) {
            short8 bh[4], bl[4];
            #pragma unroll
            for (int n = 0; n < 4; ++n) {
                int off = ((n * 4 + s) * 64 + L) * 8;
                bh[n] = *(const short8*)(Bs + off);
                bl[n] = *(const short8*)(Bs + 8192 + off);
            }
            #pragma unroll
            for (int n = 0; n < 4; ++n) {
                #pragma unroll
                for (int mt = 0; mt < 2; ++mt) {
                    acc[mt][n] = __builtin_amdgcn_mfma_f32_16x16x32_bf16(ah[mt][s], bh[n], acc[mt][n], 0, 0, 0);
                    acc[mt][n] = __builtin_amdgcn_mfma_f32_16x16x32_bf16(al[mt][s], bh[n], acc[mt][n], 0, 0, 0);
                    acc[mt][n] = __builtin_amdgcn_mfma_f32_16x16x32_bf16(ah[mt][s], bl[n], acc[mt][n], 0, 0, 0);
                }
            }
        }

        // ---- fold into running top-2 (ascending code idx => first-min) ----
        #pragma unroll
        for (int n = 0; n < 4; ++n) {
            int ci = q * 64 + n * 16 + col;
            #pragma unroll
            for (int mt = 0; mt < 2; ++mt) {
                #pragma unroll
                for (int r = 0; r < 4; ++r) {
                    float d = acc[mt][n][r];
                    if (d < b1[mt][r]) {
                        b2[mt][r] = b1[mt][r];
                        b1[mt][r] = d;
                        bi[mt][r] = ci;
                    } else {
                        b2[mt][r] = fminf(b2[mt][r], d);
                    }
                }
            }
        }
    }

    // ---- cross-lane merge of sorted top-2 pairs over the 16 lanes ----
    #pragma unroll
    for (int mt = 0; mt < 2; ++mt) {
        #pragma unroll
        for (int r = 0; r < 4; ++r) {
            float bd = b1[mt][r];
            float s2 = b2[mt][r];
            int   ii = bi[mt][r];
            #pragma unroll
            for (int m = 1; m < 16; m <<= 1) {
                float ob  = __shfl_xor(bd, m);
                int   oi  = __shfl_xor(ii, m);
                float os2 = __shfl_xor(s2, m);
                float hi  = fmaxf(bd, ob);
                s2 = fminf(hi, fminf(s2, os2));   // exact combined second-best
                if (ob < bd || (ob == bd && oi < ii)) { bd = ob; ii = oi; }
            }
            if (col == 0) {
                int tok = n0 + w * 32 + mt * 16 + quad * 4 + r;
                code_i[tok] = ii;
                code_f[tok] = (float)ii;
                atomicAdd(cnt + ii, 1);
                if (s2 - bd < MARGIN_) {          // true top-2 gap below guard band
                    int p = atomicAdd(rcnt, 1);
                    rlist[p] = tok;
                }
            }
        }
    }
}

// -------------------------------------------------------------------
// exact fp32 re-argmin for near-tie tokens; patch code + histogram
__launch_bounds__(256)
__global__ void k_fix(const float* __restrict__ x, const float* __restrict__ Et,
                      const float* __restrict__ e2, const int* __restrict__ rcnt,
                      const int* __restrict__ rlist, int* __restrict__ code_i,
                      float* __restrict__ code_f, int* __restrict__ cnt) {
    __shared__ float4 xs[32];
    __shared__ float rd[256];
    __shared__ int   ri[256];
    int tid = threadIdx.x;
    int nr = *rcnt;
    for (int it = blockIdx.x; it < nr; it += gridDim.x) {
        __syncthreads();
        int tok = rlist[it];
        if (tid < 32) xs[tid] = ((const float4*)(x + (size_t)tok * D_))[tid];
        __syncthreads();
        float bd = INFINITY; int bb = 0;
        for (int c = tid; c < K_; c += 256) {
            const float4* er = (const float4*)(Et + c * D_);
            float dot = 0.f;
            #pragma unroll 8
            for (int j = 0; j < 32; ++j) {
                float4 e = er[j], xx = xs[j];
                dot = fmaf(xx.x, e.x, dot);
                dot = fmaf(xx.y, e.y, dot);
                dot = fmaf(xx.z, e.z, dot);
                dot = fmaf(xx.w, e.w, dot);
            }
            float dist = e2[c] - 2.f * dot;
            if (dist < bd) { bd = dist; bb = c; }   // c ascending per thread
        }
        rd[tid] = bd; ri[tid] = bb;
        __syncthreads();
        for (int off = 128; off > 0; off >>= 1) {
            if (tid < off) {
                float d2 = rd[tid + off]; int i2 = ri[tid + off];
                if (d2 < rd[tid] || (d2 == rd[tid] && i2 < ri[tid])) { rd[tid] = d2; ri[tid] = i2; }
            }
            __syncthreads();
        }
        if (tid == 0) {
            int nb = ri[0], ob = code_i[tok];
            if (nb != ob) {
                code_i[tok] = nb;
                code_f[tok] = (float)nb;
                atomicAdd(cnt + ob, -1);
                atomicAdd(cnt + nb, 1);
            }
        }
    }
}

// -------------------------------------------------------------------
// exclusive scan of code histogram -> base, cursor
__launch_bounds__(1024)
__global__ void k_scan(const int* __restrict__ cnt, int* __restrict__ base,
                       int* __restrict__ cursor) {
    int k = threadIdx.x;
    __shared__ int sc[1024];
    int c = cnt[k];
    sc[k] = c;
    __syncthreads();
    for (int off = 1; off < 1024; off <<= 1) {
        int v = (k >= off) ? sc[k - off] : 0;
        __syncthreads();
        sc[k] += v;
        __syncthreads();
    }
    int inc = sc[k];
    base[k + 1] = inc;
    cursor[k]   = inc - c;   // exclusive
    if (k == 0) base[0] = 0;
}

// -------------------------------------------------------------------
// dequant gather + straight-through + diff partial + token-index scatter
__launch_bounds__(256)
__global__ void k_gather(const float* __restrict__ x, const float* __restrict__ Et,
                         const int* __restrict__ code_i, float* __restrict__ outq,
                         int* __restrict__ cursor, int* __restrict__ order,
                         float* __restrict__ ssq) {
    int e4 = blockIdx.x * 256 + threadIdx.x;   // float4 index over N*D/4
    int n = e4 >> 5, q = e4 & 31;
    int c = code_i[n];
    float4 xi = ((const float4*)x)[e4];
    float4 qv = ((const float4*)Et)[c * 32 + q];
    float4 qs;  // straight-through: x + (q - x), matching reference rounding
    qs.x = xi.x + (qv.x - xi.x);
    qs.y = xi.y + (qv.y - xi.y);
    qs.z = xi.z + (qv.z - xi.z);
    qs.w = xi.w + (qv.w - xi.w);
    ((float4*)outq)[e4] = qs;
    float dx = qs.x - xi.x, dy = qs.y - xi.y, dz = qs.z - xi.z, dw = qs.w - xi.w;
    float loc = dx * dx + dy * dy + dz * dz + dw * dw;

    if (q == 0) {
        int pos = atomicAdd(cursor + c, 1);
        order[pos] = n;
    }

    // block reduction of squared-diff
    #pragma unroll
    for (int off = 32; off > 0; off >>= 1) loc += __shfl_down(loc, off);
    __shared__ float wsum[4];
    if ((threadIdx.x & 63) == 0) wsum[threadIdx.x >> 6] = loc;
    __syncthreads();
    if (threadIdx.x == 0) atomicAdd(ssq, wsum[0] + wsum[1] + wsum[2] + wsum[3]);
}

// -------------------------------------------------------------------
// segment sum via sorted token lists: block (c, s) sums 1/SSPLIT of code c
__launch_bounds__(128)
__global__ void k_segsum(const float* __restrict__ x, const int* __restrict__ order,
                         const int* __restrict__ base, float* __restrict__ part) {
    int c = blockIdx.x, s = blockIdx.y, d = threadIdx.x;
    int b0 = base[c], b1 = base[c + 1];
    int cnt = b1 - b0;
    int i0 = b0 + (cnt * s) / SSPLIT;
    int i1 = b0 + (cnt * (s + 1)) / SSPLIT;
    float a0 = 0.f, a1 = 0.f, a2 = 0.f, a3 = 0.f;
    int i = i0;
    for (; i + 4 <= i1; i += 4) {
        int n0 = order[i], n1 = order[i + 1], n2 = order[i + 2], n3 = order[i + 3];
        a0 += x[(size_t)n0 * D_ + d];
        a1 += x[(size_t)n1 * D_ + d];
        a2 += x[(size_t)n2 * D_ + d];
        a3 += x[(size_t)n3 * D_ + d];
    }
    for (; i < i1; ++i) a0 += x[(size_t)order[i] * D_ + d];
    part[((size_t)s * K_ + c) * D_ + d] = (a0 + a1) + (a2 + a3);
}

// -------------------------------------------------------------------
// EMA cluster size, n-reduction, Laplace smoothing, diff finalize
__launch_bounds__(1024)
__global__ void k_stats(const float* __restrict__ cluster_size, const int* __restrict__ cnt,
                        const float* __restrict__ ssq, float* __restrict__ out_ncs,
                        float* __restrict__ out_diff, float* __restrict__ cs) {
    int k = threadIdx.x;
    float ncs = cluster_size[k] * DECAY_ + OMD_ * (float)cnt[k];
    out_ncs[k] = ncs;
    __shared__ float red[1024];
    red[k] = ncs;
    __syncthreads();
    for (int off = 512; off > 0; off >>= 1) {
        if (k < off) red[k] += red[k + off];
        __syncthreads();
    }
    float n = red[0];
    cs[k] = (ncs + EPS_) / (n + (float)K_ * EPS_) * n;
    if (k == 0) *out_diff = VQC_ * (*ssq) / (float)(N_ * D_);
}

// -------------------------------------------------------------------
// reduce partials; new_embedding_mean = EMA; new_embedding = mean / cs
__global__ void k_embed(const float* __restrict__ emb_mean_in, const float* __restrict__ part,
                        const float* __restrict__ cs, float* __restrict__ out_nmean,
                        float* __restrict__ out_nemb) {
    int i = blockIdx.x * 256 + threadIdx.x;   // over D*K, layout [D][K]
    int k = i & (K_ - 1);
    int d = i >> 10;
    float es = 0.f;
    #pragma unroll
    for (int s = 0; s < SSPLIT; ++s) es += part[((size_t)s * K_ + k) * D_ + d];
    float nm = emb_mean_in[i] * DECAY_ + OMD_ * es;
    out_nmean[i] = nm;
    out_nemb[i]  = nm / cs[k];
}

// -------------------------------------------------------------------
extern "C" void kernel_launch(void* const* d_in, const int* in_sizes, int n_in,
                              void* d_out, int out_size, void* d_ws, size_t ws_size,
                              hipStream_t stream) {
    const float* x   = (const float*)d_in[0];   // [16,4096,128]
    const float* E   = (const float*)d_in[1];   // [128,1024]
    const float* csz = (const float*)d_in[2];   // [1024]
    const float* em  = (const float*)d_in[3];   // [128,1024]
    float* out = (float*)d_out;
    float* W   = (float*)d_ws;

    int*   code_i = (int*)(W + WOFF_CODE);
    float* e2     = W + WOFF_E2;
    int*   cnt    = (int*)(W + WOFF_CNT);
    float* ssq    = W + WOFF_SSQ;
    int*   rcnt   = (int*)(W + WOFF_RCNT);
    int*   base   = (int*)(W + WOFF_BASE);
    int*   cursor = (int*)(W + WOFF_CURS);
    int*   order  = (int*)(W + WOFF_ORDER);
    float* cs     = W + WOFF_CS;
    float* Et     = W + WOFF_ET;
    float* part   = W + WOFF_PART;
    int*   rlist  = (int*)(W + WOFF_RLIST);
    unsigned short* Efh = (unsigned short*)(W + WOFF_EFH);
    unsigned short* Efl = (unsigned short*)(W + WOFF_EFL);

    // zero cnt[1024] + ssq + rcnt (ws is poisoned 0xAA)
    hipMemsetAsync(cnt, 0, 1026 * sizeof(int), stream);

    k_transpose<<<dim3(32, 4), dim3(32, 8), 0, stream>>>(E, Et);
    k_e2<<<K_ / 256, 256, 0, stream>>>(E, e2);
    k_prep_ef<<<64, 256, 0, stream>>>(Et, Efh, Efl);
    k_argmin_mfma<<<N_ / 128, 256, 0, stream>>>(x, Efh, Efl, e2, code_i,
                                                out + OOFF_CODE, cnt, rcnt, rlist);
    k_fix<<<256, 256, 0, stream>>>(x, Et, e2, rcnt, rlist, code_i, out + OOFF_CODE, cnt);
    k_scan<<<1, 1024, 0, stream>>>(cnt, base, cursor);
    k_gather<<<(N_ * (D_ / 4)) / 256, 256, 0, stream>>>(x, Et, code_i, out + OOFF_Q,
                                                        cursor, order, ssq);
    k_segsum<<<dim3(K_, SSPLIT), 128, 0, stream>>>(x, order, base, part);
    k_stats<<<1, 1024, 0, stream>>>(csz, cnt, ssq, out + OOFF_NCS, out + OOFF_DIFF, cs);
    k_embed<<<(D_ * K_) / 256, 256, 0, stream>>>(em, part, cs, out + OOFF_NMEAN, out + OOFF_NEMB);
}

// Round 5
// 280.606 us; speedup vs baseline: 5.8877x; 1.2596x over previous
//
#include <hip/hip_runtime.h>
#include <math.h>

#define D_ 128
#define K_ 1024
#define N_ 65536
#define DECAY_ 0.99f
#define OMD_ 0.01f
#define EPS_ 1e-5f
#define VQC_ 0.25f
#define SSPLIT 4
#define MARGIN_ 4e-3f
#define GATHER_BLOCKS 2048

typedef __attribute__((ext_vector_type(8))) short short8;
typedef __attribute__((ext_vector_type(4))) float f32x4;

// ---- workspace offsets (in 4-byte elements) ----
#define WOFF_CODE  0          // int[65536]
#define WOFF_E2    65536      // float[1024]
#define WOFF_CNT   66560      // int[1024]
#define WOFF_SSQ   67584      // float[1]
#define WOFF_RCNT  67585      // int[1]    (CNT..RCNT zeroed in one memset)
#define WOFF_BASE  67648      // int[1025]
#define WOFF_CURS  68736      // int[1024]
#define WOFF_ORDER 69760      // int[65536]
#define WOFF_CS    135296     // float[1024]
#define WOFF_ET    136320     // float[131072] (K x D), 16B aligned
#define WOFF_PART  267392     // float[SSPLIT * 131072]
#define WOFF_RLIST 791680     // int[65536]; reused as float ssq_part[GATHER_BLOCKS] after k_fix
#define WOFF_EFH   857216     // ushort[131072] frag-ordered bf16 hi of -2E
#define WOFF_EFL   922752     // ushort[131072] frag-ordered bf16 lo
// total ~988K elements (~3.95 MB)

// ---- output offsets (in floats), reference return order ----
#define OOFF_Q     0          // [16,4096,128]
#define OOFF_DIFF  8388608    // scalar
#define OOFF_CODE  8388609    // [16,4096]
#define OOFF_NEMB  8454145    // [128,1024]
#define OOFF_NCS   8585217    // [1024]
#define OOFF_NMEAN 8586241    // [128,1024]

// RNE float->bf16, also returns residual (f - bf16(f))
__device__ __forceinline__ unsigned short bf16h(float f, float* rez) {
    unsigned u = __float_as_uint(f);
    unsigned r = (u + 0x7fffu + ((u >> 16) & 1u)) >> 16;
    *rez = f - __uint_as_float(r << 16);
    return (unsigned short)r;
}

// -------------------------------------------------------------------
// E [D][K] -> Et [K][D]
__global__ void k_transpose(const float* __restrict__ E, float* __restrict__ Et) {
    __shared__ float tile[32][33];
    int k0 = blockIdx.x * 32;
    int d0 = blockIdx.y * 32;
    int tx = threadIdx.x;            // 0..31
    for (int ty = threadIdx.y; ty < 32; ty += 8)
        tile[ty][tx] = E[(d0 + ty) * K_ + (k0 + tx)];
    __syncthreads();
    for (int ty = threadIdx.y; ty < 32; ty += 8)
        Et[(k0 + ty) * D_ + (d0 + tx)] = tile[tx][ty];
}

// e2[k] = sum_d E[d][k]^2  (coalesced over k)
__global__ void k_e2(const float* __restrict__ E, float* __restrict__ e2) {
    int k = blockIdx.x * blockDim.x + threadIdx.x;
    float s = 0.f;
    #pragma unroll 8
    for (int d = 0; d < D_; ++d) { float v = E[d * K_ + k]; s = fmaf(v, v, s); }
    e2[k] = s;
}

// -------------------------------------------------------------------
// Build fragment-ordered bf16 hi/lo planes of g = -2*E.
// Layout: index T = ((g16*4 + s)*64 + L); lane L holds code g16*16+(L&15),
// dims s*32 + (L>>4)*8 .. +8  => B-operand frag for mfma 16x16x32.
__global__ void k_prep_ef(const float* __restrict__ Et, unsigned short* __restrict__ Efh,
                          unsigned short* __restrict__ Efl) {
    int T = blockIdx.x * 256 + threadIdx.x;   // 0..16383
    int L = T & 63, s = (T >> 6) & 3, g = T >> 8;
    int code = g * 16 + (L & 15);
    int d0 = s * 32 + ((L >> 4) << 3);
    const float* src = Et + code * D_ + d0;
    unsigned short h[8], l[8];
    #pragma unroll
    for (int j = 0; j < 8; ++j) {
        float v = -2.f * src[j];
        float r;
        h[j] = bf16h(v, &r);
        float r2;
        l[j] = bf16h(r, &r2);
    }
    #pragma unroll
    for (int j = 0; j < 8; ++j) { Efh[T * 8 + j] = h[j]; Efl[T * 8 + j] = l[j]; }
}

// -------------------------------------------------------------------
// MFMA argmin: dist = e2[k] + x.(-2e) via bf16 hi/lo split (3 MFMA terms).
// Block: 256 thr / 4 waves; 128 tokens per block; codes swept in 64-chunks.
// True top-2 (b1,b2) tracked per token => exact near-tie flagging.
__launch_bounds__(256, 2)
__global__ void k_argmin_mfma(const float* __restrict__ x, const unsigned short* __restrict__ Efh,
                              const unsigned short* __restrict__ Efl, const float* __restrict__ e2,
                              int* __restrict__ code_i, float* __restrict__ code_f,
                              int* __restrict__ cnt, int* __restrict__ rcnt,
                              int* __restrict__ rlist) {
    __shared__ unsigned short Bs[16384];  // 32 KB: hi plane [0,8192), lo plane [8192,16384)
    __shared__ float e2s[K_];
    int tid = threadIdx.x;
    int w = tid >> 6, L = tid & 63, quad = L >> 4, col = L & 15;
    int n0 = blockIdx.x * 128;

    for (int i = tid; i < K_; i += 256) e2s[i] = e2[i];

    // ---- A fragments: 32 tokens/wave, converted to bf16 hi/lo in registers ----
    short8 ah[2][4], al[2][4];
    #pragma unroll
    for (int mt = 0; mt < 2; ++mt) {
        int tok = n0 + w * 32 + mt * 16 + col;
        #pragma unroll
        for (int s = 0; s < 4; ++s) {
            const float* p = x + (size_t)tok * D_ + s * 32 + quad * 8;
            float4 u0 = *(const float4*)(p);
            float4 u1 = *(const float4*)(p + 4);
            float vv[8] = {u0.x, u0.y, u0.z, u0.w, u1.x, u1.y, u1.z, u1.w};
            #pragma unroll
            for (int j = 0; j < 8; ++j) {
                float r;
                ah[mt][s][j] = (short)bf16h(vv[j], &r);
                float r2;
                al[mt][s][j] = (short)bf16h(r, &r2);
            }
        }
    }

    float b1[2][4];   // running min dist per (m-tile, reg)
    float b2[2][4];   // running second-best
    int   bi[2][4];
    #pragma unroll
    for (int mt = 0; mt < 2; ++mt)
        #pragma unroll
        for (int r = 0; r < 4; ++r) { b1[mt][r] = INFINITY; b2[mt][r] = INFINITY; bi[mt][r] = 0; }

    for (int q = 0; q < 16; ++q) {
        __syncthreads();
        // ---- stage 64-code chunk: flat 16 KB copy per plane ----
        const float4* gh = (const float4*)(Efh + q * 8192);
        const float4* gl = (const float4*)(Efl + q * 8192);
        #pragma unroll
        for (int i = 0; i < 4; ++i) {
            float4 v = gh[i * 256 + tid];
            *(float4*)(Bs + (i * 256 + tid) * 8) = v;
        }
        #pragma unroll
        for (int i = 0; i < 4; ++i) {
            float4 v = gl[i * 256 + tid];
            *(float4*)(Bs + 8192 + (i * 256 + tid) * 8) = v;
        }
        __syncthreads();

        // ---- acc init = e2 of this lane's column ----
        f32x4 acc[2][4];
        #pragma unroll
        for (int n = 0; n < 4; ++n) {
            float ev = e2s[q * 64 + n * 16 + col];
            #pragma unroll
            for (int mt = 0; mt < 2; ++mt) acc[mt][n] = (f32x4){ev, ev, ev, ev};
        }

        // ---- 96 MFMA: 4 k-steps x 4 n-tiles x 2 m-tiles x 3 split terms ----
        #pragma unroll
        for (int s = 0; s < 4; ++s) {
            short8 bh[4], bl[4];
            #pragma unroll
            for (int n = 0; n < 4; ++n) {
                int off = ((n * 4 + s) * 64 + L) * 8;
                bh[n] = *(const short8*)(Bs + off);
                bl[n] = *(const short8*)(Bs + 8192 + off);
            }
            #pragma unroll
            for (int n = 0; n < 4; ++n) {
                #pragma unroll
                for (int mt = 0; mt < 2; ++mt) {
                    acc[mt][n] = __builtin_amdgcn_mfma_f32_16x16x32_bf16(ah[mt][s], bh[n], acc[mt][n], 0, 0, 0);
                    acc[mt][n] = __builtin_amdgcn_mfma_f32_16x16x32_bf16(al[mt][s], bh[n], acc[mt][n], 0, 0, 0);
                    acc[mt][n] = __builtin_amdgcn_mfma_f32_16x16x32_bf16(ah[mt][s], bl[n], acc[mt][n], 0, 0, 0);
                }
            }
        }

        // ---- fold into running top-2 (ascending code idx => first-min) ----
        #pragma unroll
        for (int n = 0; n < 4; ++n) {
            int ci = q * 64 + n * 16 + col;
            #pragma unroll
            for (int mt = 0; mt < 2; ++mt) {
                #pragma unroll
                for (int r = 0; r < 4; ++r) {
                    float d = acc[mt][n][r];
                    if (d < b1[mt][r]) {
                        b2[mt][r] = b1[mt][r];
                        b1[mt][r] = d;
                        bi[mt][r] = ci;
                    } else {
                        b2[mt][r] = fminf(b2[mt][r], d);
                    }
                }
            }
        }
    }

    // ---- cross-lane merge of sorted top-2 pairs over the 16 lanes ----
    #pragma unroll
    for (int mt = 0; mt < 2; ++mt) {
        #pragma unroll
        for (int r = 0; r < 4; ++r) {
            float bd = b1[mt][r];
            float s2 = b2[mt][r];
            int   ii = bi[mt][r];
            #pragma unroll
            for (int m = 1; m < 16; m <<= 1) {
                float ob  = __shfl_xor(bd, m);
                int   oi  = __shfl_xor(ii, m);
                float os2 = __shfl_xor(s2, m);
                float hi  = fmaxf(bd, ob);
                s2 = fminf(hi, fminf(s2, os2));   // exact combined second-best
                if (ob < bd || (ob == bd && oi < ii)) { bd = ob; ii = oi; }
            }
            if (col == 0) {
                int tok = n0 + w * 32 + mt * 16 + quad * 4 + r;
                code_i[tok] = ii;
                code_f[tok] = (float)ii;
                atomicAdd(cnt + ii, 1);
                if (s2 - bd < MARGIN_) {          // true top-2 gap below guard band
                    int p = atomicAdd(rcnt, 1);
                    rlist[p] = tok;
                }
            }
        }
    }
}

// -------------------------------------------------------------------
// exact fp32 re-argmin for near-tie tokens; patch code + histogram
__launch_bounds__(256)
__global__ void k_fix(const float* __restrict__ x, const float* __restrict__ Et,
                      const float* __restrict__ e2, const int* __restrict__ rcnt,
                      const int* __restrict__ rlist, int* __restrict__ code_i,
                      float* __restrict__ code_f, int* __restrict__ cnt) {
    __shared__ float4 xs[32];
    __shared__ float rd[256];
    __shared__ int   ri[256];
    int tid = threadIdx.x;
    int nr = *rcnt;
    for (int it = blockIdx.x; it < nr; it += gridDim.x) {
        __syncthreads();
        int tok = rlist[it];
        if (tid < 32) xs[tid] = ((const float4*)(x + (size_t)tok * D_))[tid];
        __syncthreads();
        float bd = INFINITY; int bb = 0;
        for (int c = tid; c < K_; c += 256) {
            const float4* er = (const float4*)(Et + c * D_);
            float dot = 0.f;
            #pragma unroll 8
            for (int j = 0; j < 32; ++j) {
                float4 e = er[j], xx = xs[j];
                dot = fmaf(xx.x, e.x, dot);
                dot = fmaf(xx.y, e.y, dot);
                dot = fmaf(xx.z, e.z, dot);
                dot = fmaf(xx.w, e.w, dot);
            }
            float dist = e2[c] - 2.f * dot;
            if (dist < bd) { bd = dist; bb = c; }   // c ascending per thread
        }
        rd[tid] = bd; ri[tid] = bb;
        __syncthreads();
        for (int off = 128; off > 0; off >>= 1) {
            if (tid < off) {
                float d2 = rd[tid + off]; int i2 = ri[tid + off];
                if (d2 < rd[tid] || (d2 == rd[tid] && i2 < ri[tid])) { rd[tid] = d2; ri[tid] = i2; }
            }
            __syncthreads();
        }
        if (tid == 0) {
            int nb = ri[0], ob = code_i[tok];
            if (nb != ob) {
                code_i[tok] = nb;
                code_f[tok] = (float)nb;
                atomicAdd(cnt + ob, -1);
                atomicAdd(cnt + nb, 1);
            }
        }
    }
}

// -------------------------------------------------------------------
// exclusive scan of code histogram -> base, cursor
__launch_bounds__(1024)
__global__ void k_scan(const int* __restrict__ cnt, int* __restrict__ base,
                       int* __restrict__ cursor) {
    int k = threadIdx.x;
    __shared__ int sc[1024];
    int c = cnt[k];
    sc[k] = c;
    __syncthreads();
    for (int off = 1; off < 1024; off <<= 1) {
        int v = (k >= off) ? sc[k - off] : 0;
        __syncthreads();
        sc[k] += v;
        __syncthreads();
    }
    int inc = sc[k];
    base[k + 1] = inc;
    cursor[k]   = inc - c;   // exclusive
    if (k == 0) base[0] = 0;
}

// -------------------------------------------------------------------
// dequant gather + straight-through + diff partial + token-index scatter.
// Grid-stride over GATHER_BLOCKS blocks; per-block ssq partial -> plain store
// (same-address atomicAdd serialized ~8192 RMWs = the old 112 us).
__launch_bounds__(256)
__global__ void k_gather(const float* __restrict__ x, const float* __restrict__ Et,
                         const int* __restrict__ code_i, float* __restrict__ outq,
                         int* __restrict__ cursor, int* __restrict__ order,
                         float* __restrict__ ssq_part) {
    float loc = 0.f;
    for (int e4 = blockIdx.x * 256 + threadIdx.x; e4 < N_ * 32; e4 += GATHER_BLOCKS * 256) {
        int n = e4 >> 5, q = e4 & 31;
        int c = code_i[n];
        float4 xi = ((const float4*)x)[e4];
        float4 qv = ((const float4*)Et)[c * 32 + q];
        float4 qs;  // straight-through: x + (q - x), matching reference rounding
        qs.x = xi.x + (qv.x - xi.x);
        qs.y = xi.y + (qv.y - xi.y);
        qs.z = xi.z + (qv.z - xi.z);
        qs.w = xi.w + (qv.w - xi.w);
        ((float4*)outq)[e4] = qs;
        float dx = qs.x - xi.x, dy = qs.y - xi.y, dz = qs.z - xi.z, dw = qs.w - xi.w;
        loc += dx * dx + dy * dy + dz * dz + dw * dw;

        if (q == 0) {
            int pos = atomicAdd(cursor + c, 1);
            order[pos] = n;
        }
    }

    // block reduction of squared-diff -> one plain store per block
    #pragma unroll
    for (int off = 32; off > 0; off >>= 1) loc += __shfl_down(loc, off);
    __shared__ float wsum[4];
    if ((threadIdx.x & 63) == 0) wsum[threadIdx.x >> 6] = loc;
    __syncthreads();
    if (threadIdx.x == 0) ssq_part[blockIdx.x] = wsum[0] + wsum[1] + wsum[2] + wsum[3];
}

// -------------------------------------------------------------------
// segment sum via sorted token lists: block (c, s) sums 1/SSPLIT of code c
__launch_bounds__(128)
__global__ void k_segsum(const float* __restrict__ x, const int* __restrict__ order,
                         const int* __restrict__ base, float* __restrict__ part) {
    int c = blockIdx.x, s = blockIdx.y, d = threadIdx.x;
    int b0 = base[c], b1 = base[c + 1];
    int cnt = b1 - b0;
    int i0 = b0 + (cnt * s) / SSPLIT;
    int i1 = b0 + (cnt * (s + 1)) / SSPLIT;
    float a0 = 0.f, a1 = 0.f, a2 = 0.f, a3 = 0.f;
    int i = i0;
    for (; i + 4 <= i1; i += 4) {
        int n0 = order[i], n1 = order[i + 1], n2 = order[i + 2], n3 = order[i + 3];
        a0 += x[(size_t)n0 * D_ + d];
        a1 += x[(size_t)n1 * D_ + d];
        a2 += x[(size_t)n2 * D_ + d];
        a3 += x[(size_t)n3 * D_ + d];
    }
    for (; i < i1; ++i) a0 += x[(size_t)order[i] * D_ + d];
    part[((size_t)s * K_ + c) * D_ + d] = (a0 + a1) + (a2 + a3);
}

// -------------------------------------------------------------------
// ssq partial reduce + EMA cluster size, n-reduction, smoothing, diff finalize
__launch_bounds__(1024)
__global__ void k_stats(const float* __restrict__ cluster_size, const int* __restrict__ cnt,
                        const float* __restrict__ ssq_part, float* __restrict__ out_ncs,
                        float* __restrict__ out_diff, float* __restrict__ cs) {
    int k = threadIdx.x;
    __shared__ float red[1024];

    // ---- reduce ssq partials ----
    float sp = ssq_part[k] + ssq_part[k + 1024];   // GATHER_BLOCKS == 2048
    red[k] = sp;
    __syncthreads();
    for (int off = 512; off > 0; off >>= 1) {
        if (k < off) red[k] += red[k + off];
        __syncthreads();
    }
    float ssqv = red[0];
    __syncthreads();

    // ---- EMA cluster size + n reduction ----
    float ncs = cluster_size[k] * DECAY_ + OMD_ * (float)cnt[k];
    out_ncs[k] = ncs;
    red[k] = ncs;
    __syncthreads();
    for (int off = 512; off > 0; off >>= 1) {
        if (k < off) red[k] += red[k + off];
        __syncthreads();
    }
    float n = red[0];
    cs[k] = (ncs + EPS_) / (n + (float)K_ * EPS_) * n;
    if (k == 0) *out_diff = VQC_ * ssqv / (float)(N_ * D_);
}

// -------------------------------------------------------------------
// reduce partials; new_embedding_mean = EMA; new_embedding = mean / cs
__global__ void k_embed(const float* __restrict__ emb_mean_in, const float* __restrict__ part,
                        const float* __restrict__ cs, float* __restrict__ out_nmean,
                        float* __restrict__ out_nemb) {
    int i = blockIdx.x * 256 + threadIdx.x;   // over D*K, layout [D][K]
    int k = i & (K_ - 1);
    int d = i >> 10;
    float es = 0.f;
    #pragma unroll
    for (int s = 0; s < SSPLIT; ++s) es += part[((size_t)s * K_ + k) * D_ + d];
    float nm = emb_mean_in[i] * DECAY_ + OMD_ * es;
    out_nmean[i] = nm;
    out_nemb[i]  = nm / cs[k];
}

// -------------------------------------------------------------------
extern "C" void kernel_launch(void* const* d_in, const int* in_sizes, int n_in,
                              void* d_out, int out_size, void* d_ws, size_t ws_size,
                              hipStream_t stream) {
    const float* x   = (const float*)d_in[0];   // [16,4096,128]
    const float* E   = (const float*)d_in[1];   // [128,1024]
    const float* csz = (const float*)d_in[2];   // [1024]
    const float* em  = (const float*)d_in[3];   // [128,1024]
    float* out = (float*)d_out;
    float* W   = (float*)d_ws;

    int*   code_i = (int*)(W + WOFF_CODE);
    float* e2     = W + WOFF_E2;
    int*   cnt    = (int*)(W + WOFF_CNT);
    int*   rcnt   = (int*)(W + WOFF_RCNT);
    int*   base   = (int*)(W + WOFF_BASE);
    int*   cursor = (int*)(W + WOFF_CURS);
    int*   order  = (int*)(W + WOFF_ORDER);
    float* cs     = W + WOFF_CS;
    float* Et     = W + WOFF_ET;
    float* part   = W + WOFF_PART;
    int*   rlist  = (int*)(W + WOFF_RLIST);
    float* ssq_part = (float*)(W + WOFF_RLIST);   // reuse: rlist dead after k_fix
    unsigned short* Efh = (unsigned short*)(W + WOFF_EFH);
    unsigned short* Efl = (unsigned short*)(W + WOFF_EFL);

    // zero cnt[1024] + ssq + rcnt (ws is poisoned 0xAA)
    hipMemsetAsync(cnt, 0, 1026 * sizeof(int), stream);

    k_transpose<<<dim3(32, 4), dim3(32, 8), 0, stream>>>(E, Et);
    k_e2<<<K_ / 256, 256, 0, stream>>>(E, e2);
    k_prep_ef<<<64, 256, 0, stream>>>(Et, Efh, Efl);
    k_argmin_mfma<<<N_ / 128, 256, 0, stream>>>(x, Efh, Efl, e2, code_i,
                                                out + OOFF_CODE, cnt, rcnt, rlist);
    k_fix<<<256, 256, 0, stream>>>(x, Et, e2, rcnt, rlist, code_i, out + OOFF_CODE, cnt);
    k_scan<<<1, 1024, 0, stream>>>(cnt, base, cursor);
    k_gather<<<GATHER_BLOCKS, 256, 0, stream>>>(x, Et, code_i, out + OOFF_Q,
                                                cursor, order, ssq_part);
    k_segsum<<<dim3(K_, SSPLIT), 128, 0, stream>>>(x, order, base, part);
    k_stats<<<1, 1024, 0, stream>>>(csz, cnt, ssq_part, out + OOFF_NCS, out + OOFF_DIFF, cs);
    k_embed<<<(D_ * K_) / 256, 256, 0, stream>>>(em, part, cs, out + OOFF_NMEAN, out + OOFF_NEMB);
}

// Round 6
// 265.770 us; speedup vs baseline: 6.2163x; 1.0558x over previous
//
#include <hip/hip_runtime.h>
#include <math.h>

#define D_ 128
#define K_ 1024
#define N_ 65536
#define DECAY_ 0.99f
#define OMD_ 0.01f
#define EPS_ 1e-5f
#define VQC_ 0.25f
#define SSPLIT 4
#define MARGIN_ 4e-3f
#define GATHER_BLOCKS 2048

typedef __attribute__((ext_vector_type(8))) short short8;
typedef __attribute__((ext_vector_type(4))) float f32x4;

// ---- workspace offsets (in 4-byte elements) ----
#define WOFF_CODE  0          // int[65536]
#define WOFF_E2    65536      // float[1024]
#define WOFF_CNT   66560      // int[1024]
#define WOFF_SSQ   67584      // float[1]
#define WOFF_RCNT  67585      // int[1]    (CNT..RCNT zeroed by k_transpose block 0)
#define WOFF_BASE  67648      // int[1025]
#define WOFF_CURS  68736      // int[1024]
#define WOFF_ORDER 69760      // int[65536]
#define WOFF_CS    135296     // float[1024]
#define WOFF_ET    136320     // float[131072] (K x D), 16B aligned
#define WOFF_PART  267392     // float[SSPLIT * 131072]
#define WOFF_RLIST 791680     // int[65536]; reused as float ssq_part[GATHER_BLOCKS] after k_fix
#define WOFF_EFH   857216     // ushort[131072] frag-ordered bf16 hi of -2E
#define WOFF_EFL   922752     // ushort[131072] frag-ordered bf16 lo
// total ~988K elements (~3.95 MB)

// ---- output offsets (in floats), reference return order ----
#define OOFF_Q     0          // [16,4096,128]
#define OOFF_DIFF  8388608    // scalar
#define OOFF_CODE  8388609    // [16,4096]
#define OOFF_NEMB  8454145    // [128,1024]
#define OOFF_NCS   8585217    // [1024]
#define OOFF_NMEAN 8586241    // [128,1024]

// RNE float->bf16, also returns residual (f - bf16(f))
__device__ __forceinline__ unsigned short bf16h(float f, float* rez) {
    unsigned u = __float_as_uint(f);
    unsigned r = (u + 0x7fffu + ((u >> 16) & 1u)) >> 16;
    *rez = f - __uint_as_float(r << 16);
    return (unsigned short)r;
}

// -------------------------------------------------------------------
// E [D][K] -> Et [K][D]; block (0,0) also zeroes cnt[1024]+ssq+rcnt
__global__ void k_transpose(const float* __restrict__ E, float* __restrict__ Et,
                            int* __restrict__ cnt) {
    __shared__ float tile[32][33];
    int k0 = blockIdx.x * 32;
    int d0 = blockIdx.y * 32;
    int tx = threadIdx.x;            // 0..31
    if (blockIdx.x == 0 && blockIdx.y == 0) {
        int t = threadIdx.y * 32 + tx;             // 0..255
        for (int i = t; i < 1026; i += 256) cnt[i] = 0;   // cnt[1024], ssq, rcnt
    }
    for (int ty = threadIdx.y; ty < 32; ty += 8)
        tile[ty][tx] = E[(d0 + ty) * K_ + (k0 + tx)];
    __syncthreads();
    for (int ty = threadIdx.y; ty < 32; ty += 8)
        Et[(k0 + ty) * D_ + (d0 + tx)] = tile[tx][ty];
}

// -------------------------------------------------------------------
// Build fragment-ordered bf16 hi/lo planes of g = -2*E, and e2[k] = sum E^2.
// Block b covers g16-group b: 16 codes x 4 s x 4 quads (256 threads).
// Layout: index T = ((g16*4 + s)*64 + L); lane L holds code g16*16+(L&15),
// dims s*32 + (L>>4)*8 .. +8  => B-operand frag for mfma 16x16x32.
__global__ void k_prep_ef(const float* __restrict__ Et, unsigned short* __restrict__ Efh,
                          unsigned short* __restrict__ Efl, float* __restrict__ e2) {
    __shared__ float e2s[16];
    int tid = threadIdx.x;
    int b = blockIdx.x;                        // 0..63
    int T = b * 256 + tid;
    int L = tid & 63, s = (tid >> 6) & 3;
    int code = b * 16 + (L & 15);
    int d0 = s * 32 + ((L >> 4) << 3);
    if (tid < 16) e2s[tid] = 0.f;
    __syncthreads();
    const float* src = Et + code * D_ + d0;
    unsigned short h[8], l[8];
    float sq = 0.f;
    #pragma unroll
    for (int j = 0; j < 8; ++j) {
        float e = src[j];
        sq = fmaf(e, e, sq);
        float v = -2.f * e;
        float r;
        h[j] = bf16h(v, &r);
        float r2;
        l[j] = bf16h(r, &r2);
    }
    #pragma unroll
    for (int j = 0; j < 8; ++j) { Efh[T * 8 + j] = h[j]; Efl[T * 8 + j] = l[j]; }
    atomicAdd(&e2s[L & 15], sq);
    __syncthreads();
    if (tid < 16) e2[b * 16 + tid] = e2s[tid];
}

// -------------------------------------------------------------------
// MFMA argmin: dist = e2[k] + x.(-2e) via bf16 hi/lo split (3 MFMA terms).
// 64 tokens/block (16/wave, 1 m-tile) -> grid 1024 = 4 blocks/CU resident.
// True top-2 (b1,b2) tracked per token => exact near-tie flagging.
__launch_bounds__(256, 4)
__global__ void k_argmin_mfma(const float* __restrict__ x, const unsigned short* __restrict__ Efh,
                              const unsigned short* __restrict__ Efl, const float* __restrict__ e2,
                              int* __restrict__ code_i, float* __restrict__ code_f,
                              int* __restrict__ cnt, int* __restrict__ rcnt,
                              int* __restrict__ rlist) {
    __shared__ unsigned short Bs[16384];  // 32 KB: hi plane [0,8192), lo plane [8192,16384)
    __shared__ float e2s[K_];
    int tid = threadIdx.x;
    int w = tid >> 6, L = tid & 63, quad = L >> 4, col = L & 15;
    int n0 = blockIdx.x * 64;

    for (int i = tid; i < K_; i += 256) e2s[i] = e2[i];

    // ---- A fragments: 16 tokens/wave, converted to bf16 hi/lo in registers ----
    short8 ah[4], al[4];
    {
        int tok = n0 + w * 16 + col;
        #pragma unroll
        for (int s = 0; s < 4; ++s) {
            const float* p = x + (size_t)tok * D_ + s * 32 + quad * 8;
            float4 u0 = *(const float4*)(p);
            float4 u1 = *(const float4*)(p + 4);
            float vv[8] = {u0.x, u0.y, u0.z, u0.w, u1.x, u1.y, u1.z, u1.w};
            #pragma unroll
            for (int j = 0; j < 8; ++j) {
                float r;
                ah[s][j] = (short)bf16h(vv[j], &r);
                float r2;
                al[s][j] = (short)bf16h(r, &r2);
            }
        }
    }

    float b1[4];   // running min dist per token row (reg r)
    float b2[4];   // running second-best
    int   bi[4];
    #pragma unroll
    for (int r = 0; r < 4; ++r) { b1[r] = INFINITY; b2[r] = INFINITY; bi[r] = 0; }

    for (int q = 0; q < 16; ++q) {
        __syncthreads();
        // ---- stage 64-code chunk: flat 16 KB copy per plane ----
        const float4* gh = (const float4*)(Efh + q * 8192);
        const float4* gl = (const float4*)(Efl + q * 8192);
        #pragma unroll
        for (int i = 0; i < 4; ++i) {
            float4 v = gh[i * 256 + tid];
            *(float4*)(Bs + (i * 256 + tid) * 8) = v;
        }
        #pragma unroll
        for (int i = 0; i < 4; ++i) {
            float4 v = gl[i * 256 + tid];
            *(float4*)(Bs + 8192 + (i * 256 + tid) * 8) = v;
        }
        __syncthreads();

        // ---- acc init = e2 of this lane's column ----
        f32x4 acc[4];
        #pragma unroll
        for (int n = 0; n < 4; ++n) {
            float ev = e2s[q * 64 + n * 16 + col];
            acc[n] = (f32x4){ev, ev, ev, ev};
        }

        // ---- 48 MFMA: 4 k-steps x 4 n-tiles x 3 split terms ----
        #pragma unroll
        for (int s = 0; s < 4; ++s) {
            short8 bh[4], bl[4];
            #pragma unroll
            for (int n = 0; n < 4; ++n) {
                int off = ((n * 4 + s) * 64 + L) * 8;
                bh[n] = *(const short8*)(Bs + off);
                bl[n] = *(const short8*)(Bs + 8192 + off);
            }
            #pragma unroll
            for (int n = 0; n < 4; ++n) {
                acc[n] = __builtin_amdgcn_mfma_f32_16x16x32_bf16(ah[s], bh[n], acc[n], 0, 0, 0);
                acc[n] = __builtin_amdgcn_mfma_f32_16x16x32_bf16(al[s], bh[n], acc[n], 0, 0, 0);
                acc[n] = __builtin_amdgcn_mfma_f32_16x16x32_bf16(ah[s], bl[n], acc[n], 0, 0, 0);
            }
        }

        // ---- fold into running top-2 (ascending code idx => first-min) ----
        #pragma unroll
        for (int n = 0; n < 4; ++n) {
            int ci = q * 64 + n * 16 + col;
            #pragma unroll
            for (int r = 0; r < 4; ++r) {
                float d = acc[n][r];
                if (d < b1[r]) {
                    b2[r] = b1[r];
                    b1[r] = d;
                    bi[r] = ci;
                } else {
                    b2[r] = fminf(b2[r], d);
                }
            }
        }
    }

    // ---- cross-lane merge of sorted top-2 pairs over the 16 cols ----
    #pragma unroll
    for (int r = 0; r < 4; ++r) {
        float bd = b1[r];
        float s2 = b2[r];
        int   ii = bi[r];
        #pragma unroll
        for (int m = 1; m < 16; m <<= 1) {
            float ob  = __shfl_xor(bd, m);
            int   oi  = __shfl_xor(ii, m);
            float os2 = __shfl_xor(s2, m);
            float hi  = fmaxf(bd, ob);
            s2 = fminf(hi, fminf(s2, os2));   // exact combined second-best
            if (ob < bd || (ob == bd && oi < ii)) { bd = ob; ii = oi; }
        }
        if (col == 0) {
            int tok = n0 + w * 16 + quad * 4 + r;
            code_i[tok] = ii;
            code_f[tok] = (float)ii;
            atomicAdd(cnt + ii, 1);
            if (s2 - bd < MARGIN_) {          // true top-2 gap below guard band
                int p = atomicAdd(rcnt, 1);
                rlist[p] = tok;
            }
        }
    }
}

// -------------------------------------------------------------------
// exact fp32 re-argmin for near-tie tokens; patch code + histogram
__launch_bounds__(256)
__global__ void k_fix(const float* __restrict__ x, const float* __restrict__ Et,
                      const float* __restrict__ e2, const int* __restrict__ rcnt,
                      const int* __restrict__ rlist, int* __restrict__ code_i,
                      float* __restrict__ code_f, int* __restrict__ cnt) {
    __shared__ float4 xs[32];
    __shared__ float rd[256];
    __shared__ int   ri[256];
    int tid = threadIdx.x;
    int nr = *rcnt;
    for (int it = blockIdx.x; it < nr; it += gridDim.x) {
        __syncthreads();
        int tok = rlist[it];
        if (tid < 32) xs[tid] = ((const float4*)(x + (size_t)tok * D_))[tid];
        __syncthreads();
        float bd = INFINITY; int bb = 0;
        for (int c = tid; c < K_; c += 256) {
            const float4* er = (const float4*)(Et + c * D_);
            float dot = 0.f;
            #pragma unroll 8
            for (int j = 0; j < 32; ++j) {
                float4 e = er[j], xx = xs[j];
                dot = fmaf(xx.x, e.x, dot);
                dot = fmaf(xx.y, e.y, dot);
                dot = fmaf(xx.z, e.z, dot);
                dot = fmaf(xx.w, e.w, dot);
            }
            float dist = e2[c] - 2.f * dot;
            if (dist < bd) { bd = dist; bb = c; }   // c ascending per thread
        }
        rd[tid] = bd; ri[tid] = bb;
        __syncthreads();
        for (int off = 128; off > 0; off >>= 1) {
            if (tid < off) {
                float d2 = rd[tid + off]; int i2 = ri[tid + off];
                if (d2 < rd[tid] || (d2 == rd[tid] && i2 < ri[tid])) { rd[tid] = d2; ri[tid] = i2; }
            }
            __syncthreads();
        }
        if (tid == 0) {
            int nb = ri[0], ob = code_i[tok];
            if (nb != ob) {
                code_i[tok] = nb;
                code_f[tok] = (float)nb;
                atomicAdd(cnt + ob, -1);
                atomicAdd(cnt + nb, 1);
            }
        }
    }
}

// -------------------------------------------------------------------
// exclusive scan of code histogram -> base, cursor
__launch_bounds__(1024)
__global__ void k_scan(const int* __restrict__ cnt, int* __restrict__ base,
                       int* __restrict__ cursor) {
    int k = threadIdx.x;
    __shared__ int sc[1024];
    int c = cnt[k];
    sc[k] = c;
    __syncthreads();
    for (int off = 1; off < 1024; off <<= 1) {
        int v = (k >= off) ? sc[k - off] : 0;
        __syncthreads();
        sc[k] += v;
        __syncthreads();
    }
    int inc = sc[k];
    base[k + 1] = inc;
    cursor[k]   = inc - c;   // exclusive
    if (k == 0) base[0] = 0;
}

// -------------------------------------------------------------------
// dequant gather + straight-through + diff partial + token-index scatter.
// Grid-stride; per-block ssq partial -> plain store (no same-address RMW).
__launch_bounds__(256)
__global__ void k_gather(const float* __restrict__ x, const float* __restrict__ Et,
                         const int* __restrict__ code_i, float* __restrict__ outq,
                         int* __restrict__ cursor, int* __restrict__ order,
                         float* __restrict__ ssq_part) {
    float loc = 0.f;
    for (int e4 = blockIdx.x * 256 + threadIdx.x; e4 < N_ * 32; e4 += GATHER_BLOCKS * 256) {
        int n = e4 >> 5, q = e4 & 31;
        int c = code_i[n];
        float4 xi = ((const float4*)x)[e4];
        float4 qv = ((const float4*)Et)[c * 32 + q];
        float4 qs;  // straight-through: x + (q - x), matching reference rounding
        qs.x = xi.x + (qv.x - xi.x);
        qs.y = xi.y + (qv.y - xi.y);
        qs.z = xi.z + (qv.z - xi.z);
        qs.w = xi.w + (qv.w - xi.w);
        ((float4*)outq)[e4] = qs;
        float dx = qs.x - xi.x, dy = qs.y - xi.y, dz = qs.z - xi.z, dw = qs.w - xi.w;
        loc += dx * dx + dy * dy + dz * dz + dw * dw;

        if (q == 0) {
            int pos = atomicAdd(cursor + c, 1);
            order[pos] = n;
        }
    }

    // block reduction of squared-diff -> one plain store per block
    #pragma unroll
    for (int off = 32; off > 0; off >>= 1) loc += __shfl_down(loc, off);
    __shared__ float wsum[4];
    if ((threadIdx.x & 63) == 0) wsum[threadIdx.x >> 6] = loc;
    __syncthreads();
    if (threadIdx.x == 0) ssq_part[blockIdx.x] = wsum[0] + wsum[1] + wsum[2] + wsum[3];
}

// -------------------------------------------------------------------
// segment sum via sorted token lists: block (c, s) sums 1/SSPLIT of code c
__launch_bounds__(128)
__global__ void k_segsum(const float* __restrict__ x, const int* __restrict__ order,
                         const int* __restrict__ base, float* __restrict__ part) {
    int c = blockIdx.x, s = blockIdx.y, d = threadIdx.x;
    int b0 = base[c], b1 = base[c + 1];
    int cnt = b1 - b0;
    int i0 = b0 + (cnt * s) / SSPLIT;
    int i1 = b0 + (cnt * (s + 1)) / SSPLIT;
    float a0 = 0.f, a1 = 0.f, a2 = 0.f, a3 = 0.f;
    int i = i0;
    for (; i + 4 <= i1; i += 4) {
        int n0 = order[i], n1 = order[i + 1], n2 = order[i + 2], n3 = order[i + 3];
        a0 += x[(size_t)n0 * D_ + d];
        a1 += x[(size_t)n1 * D_ + d];
        a2 += x[(size_t)n2 * D_ + d];
        a3 += x[(size_t)n3 * D_ + d];
    }
    for (; i < i1; ++i) a0 += x[(size_t)order[i] * D_ + d];
    part[((size_t)s * K_ + c) * D_ + d] = (a0 + a1) + (a2 + a3);
}

// -------------------------------------------------------------------
// ssq partial reduce + EMA cluster size, n-reduction, smoothing, diff finalize
__launch_bounds__(1024)
__global__ void k_stats(const float* __restrict__ cluster_size, const int* __restrict__ cnt,
                        const float* __restrict__ ssq_part, float* __restrict__ out_ncs,
                        float* __restrict__ out_diff, float* __restrict__ cs) {
    int k = threadIdx.x;
    __shared__ float red[1024];

    // ---- reduce ssq partials ----
    float sp = ssq_part[k] + ssq_part[k + 1024];   // GATHER_BLOCKS == 2048
    red[k] = sp;
    __syncthreads();
    for (int off = 512; off > 0; off >>= 1) {
        if (k < off) red[k] += red[k + off];
        __syncthreads();
    }
    float ssqv = red[0];
    __syncthreads();

    // ---- EMA cluster size + n reduction ----
    float ncs = cluster_size[k] * DECAY_ + OMD_ * (float)cnt[k];
    out_ncs[k] = ncs;
    red[k] = ncs;
    __syncthreads();
    for (int off = 512; off > 0; off >>= 1) {
        if (k < off) red[k] += red[k + off];
        __syncthreads();
    }
    float n = red[0];
    cs[k] = (ncs + EPS_) / (n + (float)K_ * EPS_) * n;
    if (k == 0) *out_diff = VQC_ * ssqv / (float)(N_ * D_);
}

// -------------------------------------------------------------------
// reduce partials; new_embedding_mean = EMA; new_embedding = mean / cs
__global__ void k_embed(const float* __restrict__ emb_mean_in, const float* __restrict__ part,
                        const float* __restrict__ cs, float* __restrict__ out_nmean,
                        float* __restrict__ out_nemb) {
    int i = blockIdx.x * 256 + threadIdx.x;   // over D*K, layout [D][K]
    int k = i & (K_ - 1);
    int d = i >> 10;
    float es = 0.f;
    #pragma unroll
    for (int s = 0; s < SSPLIT; ++s) es += part[((size_t)s * K_ + k) * D_ + d];
    float nm = emb_mean_in[i] * DECAY_ + OMD_ * es;
    out_nmean[i] = nm;
    out_nemb[i]  = nm / cs[k];
}

// -------------------------------------------------------------------
extern "C" void kernel_launch(void* const* d_in, const int* in_sizes, int n_in,
                              void* d_out, int out_size, void* d_ws, size_t ws_size,
                              hipStream_t stream) {
    const float* x   = (const float*)d_in[0];   // [16,4096,128]
    const float* E   = (const float*)d_in[1];   // [128,1024]
    const float* csz = (const float*)d_in[2];   // [1024]
    const float* em  = (const float*)d_in[3];   // [128,1024]
    float* out = (float*)d_out;
    float* W   = (float*)d_ws;

    int*   code_i = (int*)(W + WOFF_CODE);
    float* e2     = W + WOFF_E2;
    int*   cnt    = (int*)(W + WOFF_CNT);
    int*   rcnt   = (int*)(W + WOFF_RCNT);
    int*   base   = (int*)(W + WOFF_BASE);
    int*   cursor = (int*)(W + WOFF_CURS);
    int*   order  = (int*)(W + WOFF_ORDER);
    float* cs     = W + WOFF_CS;
    float* Et     = W + WOFF_ET;
    float* part   = W + WOFF_PART;
    int*   rlist  = (int*)(W + WOFF_RLIST);
    float* ssq_part = (float*)(W + WOFF_RLIST);   // reuse: rlist dead after k_fix
    unsigned short* Efh = (unsigned short*)(W + WOFF_EFH);
    unsigned short* Efl = (unsigned short*)(W + WOFF_EFL);

    k_transpose<<<dim3(32, 4), dim3(32, 8), 0, stream>>>(E, Et, cnt);
    k_prep_ef<<<64, 256, 0, stream>>>(Et, Efh, Efl, e2);
    k_argmin_mfma<<<N_ / 64, 256, 0, stream>>>(x, Efh, Efl, e2, code_i,
                                               out + OOFF_CODE, cnt, rcnt, rlist);
    k_fix<<<256, 256, 0, stream>>>(x, Et, e2, rcnt, rlist, code_i, out + OOFF_CODE, cnt);
    k_scan<<<1, 1024, 0, stream>>>(cnt, base, cursor);
    k_gather<<<GATHER_BLOCKS, 256, 0, stream>>>(x, Et, code_i, out + OOFF_Q,
                                                cursor, order, ssq_part);
    k_segsum<<<dim3(K_, SSPLIT), 128, 0, stream>>>(x, order, base, part);
    k_stats<<<1, 1024, 0, stream>>>(csz, cnt, ssq_part, out + OOFF_NCS, out + OOFF_DIFF, cs);
    k_embed<<<(D_ * K_) / 256, 256, 0, stream>>>(em, part, cs, out + OOFF_NMEAN, out + OOFF_NEMB);
}